// Round 6
// baseline (766.757 us; speedup 1.0000x reference)
//
#include <hip/hip_runtime.h>

#define BB 256
#define TT 1024
#define KK 64

// One block per batch item, 512 threads = 8 waves.
// Chains are SINGLE-WAVE, all-register: lane j owns state j; the all-to-all
// matvec/max uses v_readlane broadcasts (no LDS, no barriers, no waitcnt).
//   wave0: forward (exp-domain, renorm every 8 steps)  -- ve0..ve63 pinned
//   wave1: Viterbi max-only + checkpoint every 32 steps -- vc0..vc63 pinned
//   wave2: gold-path score
//   waves 3-7: park at the phase barrier
// Phase B (all 8 waves): recompute 32-step segments from checkpoints with the
// tie-exact argmax tournament (strict >, lower index wins), filling bpl.
//
// LESSON r2-r5: the scheduler SINKS loop-invariant trans loads back into the
// loop to hit its occupancy target (VGPR_Count 52/56 across attempts) -- 64
// serial L2 loads per recurrence step. float4/SROA tricks don't stop it; the
// loads are rematerializable. Fix: pass each column value through an empty
// asm volatile "+v" -- origin becomes opaque, value MUST stay in a VGPR.
__device__ __forceinline__ float rlane(float x, int i) {
  return __int_as_float(__builtin_amdgcn_readlane(__float_as_int(x), i));
}
#define RL(S, i) rlane(S, i)

__device__ __forceinline__ float wavemax(float v) {
#pragma unroll
  for (int off = 1; off <= 32; off <<= 1) v = fmaxf(v, __shfl_xor(v, off));
  return v;
}

#define REP64(M) \
  M(0) M(1) M(2) M(3) M(4) M(5) M(6) M(7) M(8) M(9) M(10) M(11) M(12) M(13) \
  M(14) M(15) M(16) M(17) M(18) M(19) M(20) M(21) M(22) M(23) M(24) M(25) \
  M(26) M(27) M(28) M(29) M(30) M(31) M(32) M(33) M(34) M(35) M(36) M(37) \
  M(38) M(39) M(40) M(41) M(42) M(43) M(44) M(45) M(46) M(47) M(48) M(49) \
  M(50) M(51) M(52) M(53) M(54) M(55) M(56) M(57) M(58) M(59) M(60) M(61) \
  M(62) M(63)

#define DECL_E(i) float ve##i = __expf(trans[(i) * KK + j]);
#define DECL_C(i) float vc##i = trans[(i) * KK + j];
#define DECL_D(i) float vd##i = trans[(i) * KK + j];

// Opaque-origin pin: compiler can no longer rematerialize/reload these.
#define PIN8(P, a, b, c, d, e, f, g, h) \
  asm volatile("" : "+v"(P##a), "+v"(P##b), "+v"(P##c), "+v"(P##d), \
                    "+v"(P##e), "+v"(P##f), "+v"(P##g), "+v"(P##h));
#define PIN64(P) \
  PIN8(P, 0, 1, 2, 3, 4, 5, 6, 7)        PIN8(P, 8, 9, 10, 11, 12, 13, 14, 15) \
  PIN8(P, 16, 17, 18, 19, 20, 21, 22, 23) PIN8(P, 24, 25, 26, 27, 28, 29, 30, 31) \
  PIN8(P, 32, 33, 34, 35, 36, 37, 38, 39) PIN8(P, 40, 41, 42, 43, 44, 45, 46, 47) \
  PIN8(P, 48, 49, 50, 51, 52, 53, 54, 55) PIN8(P, 56, 57, 58, 59, 60, 61, 62, 63)

// ---- forward: 4-way accumulated dot via readlane broadcast ----
#define FQ4(S, a, b, c, d) \
  q0 = __builtin_fmaf(RL(S, a), ve##a, q0); \
  q1 = __builtin_fmaf(RL(S, b), ve##b, q1); \
  q2 = __builtin_fmaf(RL(S, c), ve##c, q2); \
  q3 = __builtin_fmaf(RL(S, d), ve##d, q3);
#define FQALL(S) \
  FQ4(S, 0, 1, 2, 3)     FQ4(S, 4, 5, 6, 7)     FQ4(S, 8, 9, 10, 11) \
  FQ4(S, 12, 13, 14, 15) FQ4(S, 16, 17, 18, 19) FQ4(S, 20, 21, 22, 23) \
  FQ4(S, 24, 25, 26, 27) FQ4(S, 28, 29, 30, 31) FQ4(S, 32, 33, 34, 35) \
  FQ4(S, 36, 37, 38, 39) FQ4(S, 40, 41, 42, 43) FQ4(S, 44, 45, 46, 47) \
  FQ4(S, 48, 49, 50, 51) FQ4(S, 52, 53, 54, 55) FQ4(S, 56, 57, 58, 59) \
  FQ4(S, 60, 61, 62, 63)

#define FWD_STEP(T_, E_, M_) { \
  float q0 = 0.f, q1 = 0.f, q2 = 0.f, q3 = 0.f; \
  FQALL(x) \
  float q = (q0 + q1) + (q2 + q3); \
  q *= (E_); \
  q = (M_) ? q : x; \
  if (((T_) & 7) == 0) {  /* renorm by max of PRE-update s (wave-uniform) */ \
    float gm = wavemax(x); \
    q *= __builtin_amdgcn_rcpf(gm); \
    offset += __logf(gm); \
  } \
  x = q; }

#define FWD_ITER(K_, EP_, MP_) { \
  int t = tb + (K_); \
  float e = EP_; int m = MP_; \
  int tpre = t + 4; if (tpre > TT - 1) tpre = TT - 1; \
  EP_ = __expf(emb[(size_t)tpre * KK + j]); \
  MP_ = mrow[tpre]; \
  FWD_STEP(t, e, m) }

// ---- viterbi max-only (fmax is exactly associative; tree shape free) ----
#define VQ(g, a, b, c, d) float vm##g; { \
  float v0 = RL(x, a) + vc##a; \
  float v1 = RL(x, b) + vc##b; \
  float v2 = RL(x, c) + vc##c; \
  float v3 = RL(x, d) + vc##d; \
  vm##g = fmaxf(fmaxf(v0, v1), fmaxf(v2, v3)); }

#define VIT_STEP(T_, E_, M_) { \
  VQ(0, 0, 1, 2, 3)      VQ(1, 4, 5, 6, 7)      VQ(2, 8, 9, 10, 11) \
  VQ(3, 12, 13, 14, 15)  VQ(4, 16, 17, 18, 19)  VQ(5, 20, 21, 22, 23) \
  VQ(6, 24, 25, 26, 27)  VQ(7, 28, 29, 30, 31)  VQ(8, 32, 33, 34, 35) \
  VQ(9, 36, 37, 38, 39)  VQ(10, 40, 41, 42, 43) VQ(11, 44, 45, 46, 47) \
  VQ(12, 48, 49, 50, 51) VQ(13, 52, 53, 54, 55) VQ(14, 56, 57, 58, 59) \
  VQ(15, 60, 61, 62, 63) \
  float b0 = fmaxf(vm0, vm1),   b1 = fmaxf(vm2, vm3); \
  float b2 = fmaxf(vm4, vm5),   b3 = fmaxf(vm6, vm7); \
  float b4 = fmaxf(vm8, vm9),   b5 = fmaxf(vm10, vm11); \
  float b6 = fmaxf(vm12, vm13), b7 = fmaxf(vm14, vm15); \
  float best = fmaxf(fmaxf(fmaxf(b0, b1), fmaxf(b2, b3)), \
                     fmaxf(fmaxf(b4, b5), fmaxf(b6, b7))); \
  float nd = (M_) ? (best + (E_)) : x; \
  if (((T_) & 31) == 0) ckpt[(T_) >> 5][j] = nd; \
  x = nd; }

#define VIT_ITER(K_, EP_, MP_) { \
  int t = tb + (K_); \
  float e = EP_; int m = MP_; \
  int tpre = t + 4; if (tpre > TT - 1) tpre = TT - 1; \
  EP_ = emb[(size_t)tpre * KK + j]; \
  MP_ = mrow[tpre]; \
  VIT_STEP(t, e, m) }

// ---- phase-B tie-exact argmax over 8 (strict >, lower index wins) ----
#define AG(i0, i1, i2, i3, i4, i5, i6, i7) { \
  float v0 = RL(x2, i0) + vd##i0; \
  float v1 = RL(x2, i1) + vd##i1; \
  float v2 = RL(x2, i2) + vd##i2; \
  float v3 = RL(x2, i3) + vd##i3; \
  float v4 = RL(x2, i4) + vd##i4; \
  float v5 = RL(x2, i5) + vd##i5; \
  float v6 = RL(x2, i6) + vd##i6; \
  float v7 = RL(x2, i7) + vd##i7; \
  bool p0 = v1 > v0; float a0 = p0 ? v1 : v0; int n0 = p0 ? i1 : i0; \
  bool p1 = v3 > v2; float a1 = p1 ? v3 : v2; int n1 = p1 ? i3 : i2; \
  bool p2 = v5 > v4; float a2 = p2 ? v5 : v4; int n2 = p2 ? i5 : i4; \
  bool p3 = v7 > v6; float a3 = p3 ? v7 : v6; int n3 = p3 ? i7 : i6; \
  bool r0 = a1 > a0; float bb0 = r0 ? a1 : a0; int m0 = r0 ? n1 : n0; \
  bool r1 = a3 > a2; float bb1 = r1 ? a3 : a2; int m1 = r1 ? n3 : n2; \
  bool s0 = bb1 > bb0; float gg = s0 ? bb1 : bb0; int w0 = s0 ? m1 : m0; \
  bool u0 = gg > bv; bv = u0 ? gg : bv; bi = u0 ? w0 : bi; }

__global__ __launch_bounds__(512)
__attribute__((amdgpu_waves_per_eu(1, 2)))
void crf_mega_kernel(
    const float* __restrict__ em, const int* __restrict__ mask,
    const float* __restrict__ trans, const int* __restrict__ tags,
    float* __restrict__ out_dec, float* ll_sum, int* match, int* maskSum) {

  __shared__ __align__(16) float ckpt[33][KK];  // delta checkpoints (+final in [32])
  __shared__ unsigned char mrow[TT];
  __shared__ unsigned char bpl[TT][KK];         // backpointers (64 KB)
  __shared__ unsigned char segm[32][KK];
  __shared__ unsigned char bs[40];
  __shared__ int redm[32];

  const int b = blockIdx.x;
  const int tid = threadIdx.x;
  const int wv = tid >> 6;
  const int j = tid & 63;

  const float* emb = em + (size_t)b * TT * KK;
  const int* mb = mask + (size_t)b * TT;
  const int* tgb = tags + (size_t)b * TT;

  for (int t = tid; t < TT; t += 512) mrow[t] = (unsigned char)(mb[t] ? 1 : 0);
  __syncthreads();  // B0

  if (wv == 0) {
    // =========================== FORWARD (wave 0) ===========================
    REP64(DECL_E)
    PIN64(ve)
    float raw = emb[j];
    float x, offset;
    {  // ---- t = 1 special: exponentiate raw e0 with global max ----
      float m0 = wavemax(raw);
      offset = m0;
      float s = __expf(raw - m0);
      float q0 = 0.f, q1 = 0.f, q2 = 0.f, q3 = 0.f;
      FQALL(s)
      float q = (q0 + q1) + (q2 + q3);
      q *= __expf(emb[KK + j]);
      x = mrow[1] ? q : s;
    }
    float ep0 = __expf(emb[(size_t)2 * KK + j]);
    float ep1 = __expf(emb[(size_t)3 * KK + j]);
    float ep2 = __expf(emb[(size_t)4 * KK + j]);
    float ep3 = __expf(emb[(size_t)5 * KK + j]);
    int mp0 = mrow[2], mp1 = mrow[3], mp2 = mrow[4], mp3 = mrow[5];

    for (int tb = 2; tb + 3 <= TT - 1; tb += 4) {
      FWD_ITER(0, ep0, mp0)
      FWD_ITER(1, ep1, mp1)
      FWD_ITER(2, ep2, mp2)
      FWD_ITER(3, ep3, mp3)
    }
    // tail: t = 1022 (slot 0), t = 1023 (slot 1) -- static slot references
    FWD_STEP(TT - 2, ep0, mp0)
    FWD_STEP(TT - 1, ep1, mp1)

    float ssum = x;
#pragma unroll
    for (int off = 1; off <= 32; off <<= 1) ssum += __shfl_xor(ssum, off);
    if (tid == 0) atomicAdd(ll_sum, -(offset + __logf(ssum)));

  } else if (wv == 1) {
    // ====================== VITERBI max-only (wave 1) ======================
    REP64(DECL_C)
    PIN64(vc)
    float x = emb[j];
    ckpt[0][j] = x;
    float ep0 = emb[(size_t)1 * KK + j];
    float ep1 = emb[(size_t)2 * KK + j];
    float ep2 = emb[(size_t)3 * KK + j];
    float ep3 = emb[(size_t)4 * KK + j];
    int mp0 = mrow[1], mp1 = mrow[2], mp2 = mrow[3], mp3 = mrow[4];

    for (int tb = 1; tb + 3 <= TT - 1; tb += 4) {
      VIT_ITER(0, ep0, mp0)
      VIT_ITER(1, ep1, mp1)
      VIT_ITER(2, ep2, mp2)
      VIT_ITER(3, ep3, mp3)
    }
    // tail: t = 1021,1022,1023 -> slots 0,1,2
    VIT_STEP(TT - 3, ep0, mp0)
    VIT_STEP(TT - 2, ep1, mp1)
    VIT_STEP(TT - 1, ep2, mp2)

    ckpt[32][j] = x;   // final delta for last-tag argmax

  } else if (wv == 2) {
    // ========================= PATH SCORE (wave 2) =========================
    float acc = 0.f;
    int cnt = 0;
    for (int t = j; t < TT; t += 64) {
      if (mb[t]) {
        int tg = tgb[t];
        acc += emb[(size_t)t * KK + tg];
        cnt += 1;
        if (t >= 1) acc += trans[tgb[t - 1] * KK + tg];
      }
    }
#pragma unroll
    for (int off = 1; off <= 32; off <<= 1) {
      acc += __shfl_xor(acc, off);
      cnt += __shfl_xor(cnt, off);
    }
    if (j == 0) { atomicAdd(ll_sum, acc); atomicAdd(maskSum, cnt); }
  }
  // waves 3-7 fall through.

  __syncthreads();  // B1 — phase boundary

  // D loaded (and pinned) AFTER B1 so its registers never overlap the chains.
  REP64(DECL_D)
  PIN64(vd)

  // ====== PHASE B: per-segment argmax recompute (8 waves x 4 segments) ======
#pragma unroll 1
  for (int kk = 0; kk < 4; ++kk) {
    int s = wv + 8 * kk;
    int tS = 32 * s + 1;
    int tE = (s == 31) ? (TT - 1) : (32 * s + 32);
    float x2 = ckpt[s][j];
    float e_nx = emb[(size_t)tS * KK + j];
#pragma unroll 1
    for (int t = tS; t <= tE; ++t) {
      float e = e_nx;
      if (t < tE) e_nx = emb[(size_t)(t + 1) * KK + j];
      float bv = -__builtin_inff(); int bi = 0;
      AG(0, 1, 2, 3, 4, 5, 6, 7)        AG(8, 9, 10, 11, 12, 13, 14, 15)
      AG(16, 17, 18, 19, 20, 21, 22, 23) AG(24, 25, 26, 27, 28, 29, 30, 31)
      AG(32, 33, 34, 35, 36, 37, 38, 39) AG(40, 41, 42, 43, 44, 45, 46, 47)
      AG(48, 49, 50, 51, 52, 53, 54, 55) AG(56, 57, 58, 59, 60, 61, 62, 63)
      int m = mrow[t];
      float nd = m ? (bv + e) : x2;
      int bp = m ? bi : j;
      bpl[t][j] = (unsigned char)bp;
      x2 = nd;
    }
  }
  __syncthreads();  // B2

  // ---- compose 32-step segment maps (4 chains per thread, ILP) ----
  {
    int j0 = tid & 63;
    int sg = tid >> 6;     // 0..7
    int xs[4]; int tS[4], tE[4];
#pragma unroll
    for (int kk = 0; kk < 4; ++kk) {
      int s = sg + 8 * kk;
      xs[kk] = j0;
      tS[kk] = 32 * s + 1;
      tE[kk] = (s == 31) ? (TT - 1) : (32 * s + 32);
    }
    for (int q = 0; q < 32; ++q) {
#pragma unroll
      for (int kk = 0; kk < 4; ++kk) {
        int t = tE[kk] - q;
        if (t >= tS[kk]) xs[kk] = bpl[t][xs[kk]];
      }
    }
#pragma unroll
    for (int kk = 0; kk < 4; ++kk) segm[sg + 8 * kk][j0] = (unsigned char)xs[kk];
  }
  __syncthreads();  // B3

  if (tid == 0) {   // last_tag argmax (strict >, first max) + boundary walk
    float bd = ckpt[32][0];
    int lt = 0;
    for (int i = 1; i < KK; ++i) {
      float v2 = ckpt[32][i];
      if (v2 > bd) { bd = v2; lt = i; }
    }
    bs[32] = (unsigned char)lt;
    for (int s = 31; s >= 0; --s) bs[s] = segm[s][bs[s + 1]];
  }
  __syncthreads();  // B4

  if (tid < 32) {   // per-segment backtrace
    int s = tid;
    int x = bs[s + 1];
    int cnt = 0;
    int tEnd = (s == 31) ? (TT - 1) : (32 * s + 32);
    if (s == 31) {
      int m = mrow[TT - 1];
      out_dec[(size_t)b * TT + TT - 1] = (float)(m ? x : 0);
      cnt += (m && x == tgb[TT - 1]);
    }
    for (int t = tEnd; t >= 32 * s + 1; --t) {
      x = bpl[t][x];
      int m2 = mrow[t - 1];
      out_dec[(size_t)b * TT + t - 1] = (float)(m2 ? x : 0);
      cnt += (m2 && x == tgb[t - 1]);
    }
    redm[s] = cnt;
  }
  __syncthreads();  // B5
  if (tid == 0) {
    int c = 0;
    for (int s = 0; s < 32; ++s) c += redm[s];
    atomicAdd(match, c);
  }
}

__global__ void finalize_kernel(const float* ll_sum, const int* match,
                                const int* maskSum, float* d_out) {
  d_out[0] = -(*ll_sum) / (float)BB;
  d_out[1 + BB * TT] = (float)(*match) / (float)(*maskSum);
}

extern "C" void kernel_launch(void* const* d_in, const int* in_sizes, int n_in,
                              void* d_out, int out_size, void* d_ws, size_t ws_size,
                              hipStream_t stream) {
  const float* em = (const float*)d_in[0];
  const int* tags = (const int*)d_in[1];
  const int* mask = (const int*)d_in[2];       // bool -> int32 on device
  const float* trans = (const float*)d_in[3];
  float* out = (float*)d_out;

  float* ll_sum = (float*)d_ws;
  int* match = (int*)((char*)d_ws + 4);
  int* maskSum = (int*)((char*)d_ws + 8);

  hipMemsetAsync(d_ws, 0, 12, stream);
  crf_mega_kernel<<<BB, 512, 0, stream>>>(em, mask, trans, tags, out + 1,
                                          ll_sum, match, maskSum);
  finalize_kernel<<<1, 1, 0, stream>>>(ll_sum, match, maskSum, out);
}

// Round 7
// 762.724 us; speedup vs baseline: 1.0053x; 1.0053x over previous
//
#include <hip/hip_runtime.h>

#define BB 256
#define TT 1024
#define KK 64

// One block per batch item, 512 threads = 8 waves.
// Chains are SINGLE-WAVE, all-register: lane j owns state j; the all-to-all
// matvec/max uses v_readlane broadcasts (no LDS, no barriers, no waitcnt).
// The 64x64 transition matrix lives in 64 WAVE registers: ve_i[lane j] =
// T[i][j] (row i spread across lanes) -- 64 VGPRs total per wave.
//   wave0: forward (exp-domain, renorm every 8 steps)
//   wave1: Viterbi max-only + checkpoint every 32 steps
//   wave2: gold-path score
//   waves 3-7: park at the phase barrier
// Phase B (all 8 waves): recompute 32-step segments from checkpoints with the
// tie-exact argmax tournament (strict >, lower index wins), filling bpl.
//
// LESSON r2-r6: the allocator spills the 64 loop-invariant rows to scratch
// and reloads each before its single use (live set ~12, VGPR_Count 52-56),
// putting 64 serial reloads on every recurrence step. A pin BEFORE the loop
// does not help (legal to spill after it). Fix: KEEP64 -- one asm with all
// 64 values as simultaneous inputs INSIDE the loop body, every iteration.
__device__ __forceinline__ float rlane(float x, int i) {
  return __int_as_float(__builtin_amdgcn_readlane(__float_as_int(x), i));
}
#define RL(S, i) rlane(S, i)

__device__ __forceinline__ float wavemax(float v) {
#pragma unroll
  for (int off = 1; off <= 32; off <<= 1) v = fmaxf(v, __shfl_xor(v, off));
  return v;
}

#define REP64(M) \
  M(0) M(1) M(2) M(3) M(4) M(5) M(6) M(7) M(8) M(9) M(10) M(11) M(12) M(13) \
  M(14) M(15) M(16) M(17) M(18) M(19) M(20) M(21) M(22) M(23) M(24) M(25) \
  M(26) M(27) M(28) M(29) M(30) M(31) M(32) M(33) M(34) M(35) M(36) M(37) \
  M(38) M(39) M(40) M(41) M(42) M(43) M(44) M(45) M(46) M(47) M(48) M(49) \
  M(50) M(51) M(52) M(53) M(54) M(55) M(56) M(57) M(58) M(59) M(60) M(61) \
  M(62) M(63)

#define DECL_E(i) float ve##i = __expf(trans[(i) * KK + j]);
#define DECL_C(i) float vc##i = trans[(i) * KK + j];
#define DECL_D(i) float vd##i = trans[(i) * KK + j];

// Force all 64 rows simultaneously live in VGPRs at this program point.
// Placed INSIDE each loop body so spill-reload per use is never profitable.
#define KEEP64(P) asm volatile("" :: \
  "v"(P##0),  "v"(P##1),  "v"(P##2),  "v"(P##3),  "v"(P##4),  "v"(P##5),  \
  "v"(P##6),  "v"(P##7),  "v"(P##8),  "v"(P##9),  "v"(P##10), "v"(P##11), \
  "v"(P##12), "v"(P##13), "v"(P##14), "v"(P##15), "v"(P##16), "v"(P##17), \
  "v"(P##18), "v"(P##19), "v"(P##20), "v"(P##21), "v"(P##22), "v"(P##23), \
  "v"(P##24), "v"(P##25), "v"(P##26), "v"(P##27), "v"(P##28), "v"(P##29), \
  "v"(P##30), "v"(P##31), "v"(P##32), "v"(P##33), "v"(P##34), "v"(P##35), \
  "v"(P##36), "v"(P##37), "v"(P##38), "v"(P##39), "v"(P##40), "v"(P##41), \
  "v"(P##42), "v"(P##43), "v"(P##44), "v"(P##45), "v"(P##46), "v"(P##47), \
  "v"(P##48), "v"(P##49), "v"(P##50), "v"(P##51), "v"(P##52), "v"(P##53), \
  "v"(P##54), "v"(P##55), "v"(P##56), "v"(P##57), "v"(P##58), "v"(P##59), \
  "v"(P##60), "v"(P##61), "v"(P##62), "v"(P##63));

// ---- forward: 4-way accumulated dot via readlane broadcast ----
#define FQ4(S, a, b, c, d) \
  q0 = __builtin_fmaf(RL(S, a), ve##a, q0); \
  q1 = __builtin_fmaf(RL(S, b), ve##b, q1); \
  q2 = __builtin_fmaf(RL(S, c), ve##c, q2); \
  q3 = __builtin_fmaf(RL(S, d), ve##d, q3);
#define FQALL(S) \
  FQ4(S, 0, 1, 2, 3)     FQ4(S, 4, 5, 6, 7)     FQ4(S, 8, 9, 10, 11) \
  FQ4(S, 12, 13, 14, 15) FQ4(S, 16, 17, 18, 19) FQ4(S, 20, 21, 22, 23) \
  FQ4(S, 24, 25, 26, 27) FQ4(S, 28, 29, 30, 31) FQ4(S, 32, 33, 34, 35) \
  FQ4(S, 36, 37, 38, 39) FQ4(S, 40, 41, 42, 43) FQ4(S, 44, 45, 46, 47) \
  FQ4(S, 48, 49, 50, 51) FQ4(S, 52, 53, 54, 55) FQ4(S, 56, 57, 58, 59) \
  FQ4(S, 60, 61, 62, 63)

#define FWD_STEP(T_, E_, M_) { \
  KEEP64(ve) \
  float q0 = 0.f, q1 = 0.f, q2 = 0.f, q3 = 0.f; \
  FQALL(x) \
  float q = (q0 + q1) + (q2 + q3); \
  q *= (E_); \
  q = (M_) ? q : x; \
  if (((T_) & 7) == 0) {  /* renorm by max of PRE-update s (wave-uniform) */ \
    float gm = wavemax(x); \
    q *= __builtin_amdgcn_rcpf(gm); \
    offset += __logf(gm); \
  } \
  x = q; }

#define FWD_ITER(K_, EP_, MP_) { \
  int t = tb + (K_); \
  float e = EP_; int m = MP_; \
  int tpre = t + 4; if (tpre > TT - 1) tpre = TT - 1; \
  EP_ = __expf(emb[(size_t)tpre * KK + j]); \
  MP_ = mrow[tpre]; \
  FWD_STEP(t, e, m) }

// ---- viterbi max-only (fmax is exactly associative; tree shape free) ----
#define VQ(g, a, b, c, d) float vm##g; { \
  float v0 = RL(x, a) + vc##a; \
  float v1 = RL(x, b) + vc##b; \
  float v2 = RL(x, c) + vc##c; \
  float v3 = RL(x, d) + vc##d; \
  vm##g = fmaxf(fmaxf(v0, v1), fmaxf(v2, v3)); }

#define VIT_STEP(T_, E_, M_) { \
  KEEP64(vc) \
  VQ(0, 0, 1, 2, 3)      VQ(1, 4, 5, 6, 7)      VQ(2, 8, 9, 10, 11) \
  VQ(3, 12, 13, 14, 15)  VQ(4, 16, 17, 18, 19)  VQ(5, 20, 21, 22, 23) \
  VQ(6, 24, 25, 26, 27)  VQ(7, 28, 29, 30, 31)  VQ(8, 32, 33, 34, 35) \
  VQ(9, 36, 37, 38, 39)  VQ(10, 40, 41, 42, 43) VQ(11, 44, 45, 46, 47) \
  VQ(12, 48, 49, 50, 51) VQ(13, 52, 53, 54, 55) VQ(14, 56, 57, 58, 59) \
  VQ(15, 60, 61, 62, 63) \
  float b0 = fmaxf(vm0, vm1),   b1 = fmaxf(vm2, vm3); \
  float b2 = fmaxf(vm4, vm5),   b3 = fmaxf(vm6, vm7); \
  float b4 = fmaxf(vm8, vm9),   b5 = fmaxf(vm10, vm11); \
  float b6 = fmaxf(vm12, vm13), b7 = fmaxf(vm14, vm15); \
  float best = fmaxf(fmaxf(fmaxf(b0, b1), fmaxf(b2, b3)), \
                     fmaxf(fmaxf(b4, b5), fmaxf(b6, b7))); \
  float nd = (M_) ? (best + (E_)) : x; \
  if (((T_) & 31) == 0) ckpt[(T_) >> 5][j] = nd; \
  x = nd; }

#define VIT_ITER(K_, EP_, MP_) { \
  int t = tb + (K_); \
  float e = EP_; int m = MP_; \
  int tpre = t + 4; if (tpre > TT - 1) tpre = TT - 1; \
  EP_ = emb[(size_t)tpre * KK + j]; \
  MP_ = mrow[tpre]; \
  VIT_STEP(t, e, m) }

// ---- phase-B tie-exact argmax over 8 (strict >, lower index wins) ----
#define AG(i0, i1, i2, i3, i4, i5, i6, i7) { \
  float v0 = RL(x2, i0) + vd##i0; \
  float v1 = RL(x2, i1) + vd##i1; \
  float v2 = RL(x2, i2) + vd##i2; \
  float v3 = RL(x2, i3) + vd##i3; \
  float v4 = RL(x2, i4) + vd##i4; \
  float v5 = RL(x2, i5) + vd##i5; \
  float v6 = RL(x2, i6) + vd##i6; \
  float v7 = RL(x2, i7) + vd##i7; \
  bool p0 = v1 > v0; float a0 = p0 ? v1 : v0; int n0 = p0 ? i1 : i0; \
  bool p1 = v3 > v2; float a1 = p1 ? v3 : v2; int n1 = p1 ? i3 : i2; \
  bool p2 = v5 > v4; float a2 = p2 ? v5 : v4; int n2 = p2 ? i5 : i4; \
  bool p3 = v7 > v6; float a3 = p3 ? v7 : v6; int n3 = p3 ? i7 : i6; \
  bool r0 = a1 > a0; float bb0 = r0 ? a1 : a0; int m0 = r0 ? n1 : n0; \
  bool r1 = a3 > a2; float bb1 = r1 ? a3 : a2; int m1 = r1 ? n3 : n2; \
  bool s0 = bb1 > bb0; float gg = s0 ? bb1 : bb0; int w0 = s0 ? m1 : m0; \
  bool u0 = gg > bv; bv = u0 ? gg : bv; bi = u0 ? w0 : bi; }

__global__ __launch_bounds__(512)
__attribute__((amdgpu_waves_per_eu(1, 2)))
void crf_mega_kernel(
    const float* __restrict__ em, const int* __restrict__ mask,
    const float* __restrict__ trans, const int* __restrict__ tags,
    float* __restrict__ out_dec, float* ll_sum, int* match, int* maskSum) {

  __shared__ __align__(16) float ckpt[33][KK];  // delta checkpoints (+final in [32])
  __shared__ unsigned char mrow[TT];
  __shared__ unsigned char bpl[TT][KK];         // backpointers (64 KB)
  __shared__ unsigned char segm[32][KK];
  __shared__ unsigned char bs[40];
  __shared__ int redm[32];

  const int b = blockIdx.x;
  const int tid = threadIdx.x;
  const int wv = tid >> 6;
  const int j = tid & 63;

  const float* emb = em + (size_t)b * TT * KK;
  const int* mb = mask + (size_t)b * TT;
  const int* tgb = tags + (size_t)b * TT;

  for (int t = tid; t < TT; t += 512) mrow[t] = (unsigned char)(mb[t] ? 1 : 0);
  __syncthreads();  // B0

  if (wv == 0) {
    // =========================== FORWARD (wave 0) ===========================
    REP64(DECL_E)
    float raw = emb[j];
    float x, offset;
    {  // ---- t = 1 special: exponentiate raw e0 with global max ----
      float m0 = wavemax(raw);
      offset = m0;
      float s = __expf(raw - m0);
      float q0 = 0.f, q1 = 0.f, q2 = 0.f, q3 = 0.f;
      FQALL(s)
      float q = (q0 + q1) + (q2 + q3);
      q *= __expf(emb[KK + j]);
      x = mrow[1] ? q : s;
    }
    float ep0 = __expf(emb[(size_t)2 * KK + j]);
    float ep1 = __expf(emb[(size_t)3 * KK + j]);
    float ep2 = __expf(emb[(size_t)4 * KK + j]);
    float ep3 = __expf(emb[(size_t)5 * KK + j]);
    int mp0 = mrow[2], mp1 = mrow[3], mp2 = mrow[4], mp3 = mrow[5];

    for (int tb = 2; tb + 3 <= TT - 1; tb += 4) {
      FWD_ITER(0, ep0, mp0)
      FWD_ITER(1, ep1, mp1)
      FWD_ITER(2, ep2, mp2)
      FWD_ITER(3, ep3, mp3)
    }
    // tail: t = 1022 (slot 0), t = 1023 (slot 1) -- static slot references
    FWD_STEP(TT - 2, ep0, mp0)
    FWD_STEP(TT - 1, ep1, mp1)

    float ssum = x;
#pragma unroll
    for (int off = 1; off <= 32; off <<= 1) ssum += __shfl_xor(ssum, off);
    if (tid == 0) atomicAdd(ll_sum, -(offset + __logf(ssum)));

  } else if (wv == 1) {
    // ====================== VITERBI max-only (wave 1) ======================
    REP64(DECL_C)
    float x = emb[j];
    ckpt[0][j] = x;
    float ep0 = emb[(size_t)1 * KK + j];
    float ep1 = emb[(size_t)2 * KK + j];
    float ep2 = emb[(size_t)3 * KK + j];
    float ep3 = emb[(size_t)4 * KK + j];
    int mp0 = mrow[1], mp1 = mrow[2], mp2 = mrow[3], mp3 = mrow[4];

    for (int tb = 1; tb + 3 <= TT - 1; tb += 4) {
      VIT_ITER(0, ep0, mp0)
      VIT_ITER(1, ep1, mp1)
      VIT_ITER(2, ep2, mp2)
      VIT_ITER(3, ep3, mp3)
    }
    // tail: t = 1021,1022,1023 -> slots 0,1,2
    VIT_STEP(TT - 3, ep0, mp0)
    VIT_STEP(TT - 2, ep1, mp1)
    VIT_STEP(TT - 1, ep2, mp2)

    ckpt[32][j] = x;   // final delta for last-tag argmax

  } else if (wv == 2) {
    // ========================= PATH SCORE (wave 2) =========================
    float acc = 0.f;
    int cnt = 0;
    for (int t = j; t < TT; t += 64) {
      if (mb[t]) {
        int tg = tgb[t];
        acc += emb[(size_t)t * KK + tg];
        cnt += 1;
        if (t >= 1) acc += trans[tgb[t - 1] * KK + tg];
      }
    }
#pragma unroll
    for (int off = 1; off <= 32; off <<= 1) {
      acc += __shfl_xor(acc, off);
      cnt += __shfl_xor(cnt, off);
    }
    if (j == 0) { atomicAdd(ll_sum, acc); atomicAdd(maskSum, cnt); }
  }
  // waves 3-7 fall through.

  __syncthreads();  // B1 — phase boundary

  // D loaded AFTER B1 so its registers never overlap the chain loops.
  REP64(DECL_D)

  // ====== PHASE B: per-segment argmax recompute (8 waves x 4 segments) ======
#pragma unroll 1
  for (int kk = 0; kk < 4; ++kk) {
    int s = wv + 8 * kk;
    int tS = 32 * s + 1;
    int tE = (s == 31) ? (TT - 1) : (32 * s + 32);
    float x2 = ckpt[s][j];
    float e_nx = emb[(size_t)tS * KK + j];
#pragma unroll 1
    for (int t = tS; t <= tE; ++t) {
      float e = e_nx;
      if (t < tE) e_nx = emb[(size_t)(t + 1) * KK + j];
      KEEP64(vd)
      float bv = -__builtin_inff(); int bi = 0;
      AG(0, 1, 2, 3, 4, 5, 6, 7)        AG(8, 9, 10, 11, 12, 13, 14, 15)
      AG(16, 17, 18, 19, 20, 21, 22, 23) AG(24, 25, 26, 27, 28, 29, 30, 31)
      AG(32, 33, 34, 35, 36, 37, 38, 39) AG(40, 41, 42, 43, 44, 45, 46, 47)
      AG(48, 49, 50, 51, 52, 53, 54, 55) AG(56, 57, 58, 59, 60, 61, 62, 63)
      int m = mrow[t];
      float nd = m ? (bv + e) : x2;
      int bp = m ? bi : j;
      bpl[t][j] = (unsigned char)bp;
      x2 = nd;
    }
  }
  __syncthreads();  // B2

  // ---- compose 32-step segment maps (4 chains per thread, ILP) ----
  {
    int j0 = tid & 63;
    int sg = tid >> 6;     // 0..7
    int xs[4]; int tS[4], tE[4];
#pragma unroll
    for (int kk = 0; kk < 4; ++kk) {
      int s = sg + 8 * kk;
      xs[kk] = j0;
      tS[kk] = 32 * s + 1;
      tE[kk] = (s == 31) ? (TT - 1) : (32 * s + 32);
    }
    for (int q = 0; q < 32; ++q) {
#pragma unroll
      for (int kk = 0; kk < 4; ++kk) {
        int t = tE[kk] - q;
        if (t >= tS[kk]) xs[kk] = bpl[t][xs[kk]];
      }
    }
#pragma unroll
    for (int kk = 0; kk < 4; ++kk) segm[sg + 8 * kk][j0] = (unsigned char)xs[kk];
  }
  __syncthreads();  // B3

  if (tid == 0) {   // last_tag argmax (strict >, first max) + boundary walk
    float bd = ckpt[32][0];
    int lt = 0;
    for (int i = 1; i < KK; ++i) {
      float v2 = ckpt[32][i];
      if (v2 > bd) { bd = v2; lt = i; }
    }
    bs[32] = (unsigned char)lt;
    for (int s = 31; s >= 0; --s) bs[s] = segm[s][bs[s + 1]];
  }
  __syncthreads();  // B4

  if (tid < 32) {   // per-segment backtrace
    int s = tid;
    int x = bs[s + 1];
    int cnt = 0;
    int tEnd = (s == 31) ? (TT - 1) : (32 * s + 32);
    if (s == 31) {
      int m = mrow[TT - 1];
      out_dec[(size_t)b * TT + TT - 1] = (float)(m ? x : 0);
      cnt += (m && x == tgb[TT - 1]);
    }
    for (int t = tEnd; t >= 32 * s + 1; --t) {
      x = bpl[t][x];
      int m2 = mrow[t - 1];
      out_dec[(size_t)b * TT + t - 1] = (float)(m2 ? x : 0);
      cnt += (m2 && x == tgb[t - 1]);
    }
    redm[s] = cnt;
  }
  __syncthreads();  // B5
  if (tid == 0) {
    int c = 0;
    for (int s = 0; s < 32; ++s) c += redm[s];
    atomicAdd(match, c);
  }
}

__global__ void finalize_kernel(const float* ll_sum, const int* match,
                                const int* maskSum, float* d_out) {
  d_out[0] = -(*ll_sum) / (float)BB;
  d_out[1 + BB * TT] = (float)(*match) / (float)(*maskSum);
}

extern "C" void kernel_launch(void* const* d_in, const int* in_sizes, int n_in,
                              void* d_out, int out_size, void* d_ws, size_t ws_size,
                              hipStream_t stream) {
  const float* em = (const float*)d_in[0];
  const int* tags = (const int*)d_in[1];
  const int* mask = (const int*)d_in[2];       // bool -> int32 on device
  const float* trans = (const float*)d_in[3];
  float* out = (float*)d_out;

  float* ll_sum = (float*)d_ws;
  int* match = (int*)((char*)d_ws + 4);
  int* maskSum = (int*)((char*)d_ws + 8);

  hipMemsetAsync(d_ws, 0, 12, stream);
  crf_mega_kernel<<<BB, 512, 0, stream>>>(em, mask, trans, tags, out + 1,
                                          ll_sum, match, maskSum);
  finalize_kernel<<<1, 1, 0, stream>>>(ll_sum, match, maskSum, out);
}